// Round 12
// baseline (169.775 us; speedup 1.0000x reference)
//
#include <hip/hip_runtime.h>
#include <math.h>

// B=4, T=512, IDIM=128, HDIM=1024, CDIM=256
#define NROWS 2048
#define NBLK  2048            // one row per block, 2 waves per block
#define NITER 4
#define IGNORE_OUT 10000.0f
#define LOG2E 1.44269504088896340736f

__device__ __forceinline__ float readlanef(float v, int lane){
  return __int_as_float(__builtin_amdgcn_readlane(__float_as_int(v), lane));
}

// ---- DPP wave primitives (gfx9 ladder) ----
__device__ __forceinline__ float waveScanInc(float v){
  v += __int_as_float(__builtin_amdgcn_update_dpp(0, __float_as_int(v), 0x111, 0xF, 0xF, true));
  v += __int_as_float(__builtin_amdgcn_update_dpp(0, __float_as_int(v), 0x112, 0xF, 0xF, true));
  v += __int_as_float(__builtin_amdgcn_update_dpp(0, __float_as_int(v), 0x114, 0xF, 0xF, true));
  v += __int_as_float(__builtin_amdgcn_update_dpp(0, __float_as_int(v), 0x118, 0xF, 0xF, true));
  v += __int_as_float(__builtin_amdgcn_update_dpp(0, __float_as_int(v), 0x142, 0xA, 0xF, true));
  v += __int_as_float(__builtin_amdgcn_update_dpp(0, __float_as_int(v), 0x143, 0xC, 0xF, true));
  return v;
}
__device__ __forceinline__ float waveSum(float v){
  return readlanef(waveScanInc(v), 63);
}
__device__ __forceinline__ void waveArgmax(float &v, int &i){
#define AMSTEP(ctrl, rm) { \
    float ov = __int_as_float(__builtin_amdgcn_update_dpp(__float_as_int(v), __float_as_int(v), ctrl, rm, 0xF, false)); \
    int   oi = __builtin_amdgcn_update_dpp(i, i, ctrl, rm, 0xF, false); \
    bool take = (ov > v) || (ov == v && oi < i); \
    v = take ? ov : v; i = take ? oi : i; }
  AMSTEP(0x111, 0xF) AMSTEP(0x112, 0xF) AMSTEP(0x114, 0xF)
  AMSTEP(0x118, 0xF) AMSTEP(0x142, 0xA) AMSTEP(0x143, 0xC)
#undef AMSTEP
  v = readlanef(v, 63);
  i = __builtin_amdgcn_readlane(i, 63);
}
// paired gather: a = vec[idx], b = vec[idx+64] (0 outside [0,128)); 2 bpermutes total
__device__ __forceinline__ void gatherPair(float v0, float v1, int idx, float &a, float &b){
  int c = idx & 63;
  float g0 = __shfl(v0, c, 64);
  float g1 = __shfl(v1, c, 64);
  a = ((unsigned)idx < 128u) ? ((idx & 64) ? g1 : g0) : 0.f;
  int idx2 = idx + 64;
  b = ((unsigned)idx2 < 128u) ? ((idx2 & 64) ? g1 : g0) : 0.f;
}

// ---------- prep kernel (unchanged from r8) ----------
__global__ __launch_bounds__(128)
void prepK(const float* __restrict__ w1, const float* __restrict__ b1,
           const float* __restrict__ w2, const float* __restrict__ b2,
           float* __restrict__ M4, float* __restrict__ biasT, int* __restrict__ ticket){
  const int blk = blockIdx.x;
  const int u = threadIdx.x;
  if (blk < 512){
    int i = blk >> 7, o = blk & 127;
    const float* w1p = w1 + (i * 256) * 128 + u;   // coalesced over d=u
    const float* w2p = w2 + o * 1024 + i * 256;    // thread-uniform
    float a = 0.f;
    #pragma unroll 16
    for (int c = 0; c < 256; ++c) a = fmaf(w1p[c * 128], w2p[c], a);
    M4[i * 16384 + (u >> 2) * 512 + o * 4 + (u & 3)] = a;
  } else if (blk < 516){
    int i = blk - 512;
    const float* w2p = w2 + u * 1024 + i * 256;
    const float* b1p = b1 + i * 256;
    float a = b2[u];
    #pragma unroll 8
    for (int c = 0; c < 256; ++c) a = fmaf(b1p[c], w2p[c], a);
    biasT[i * 128 + u] = a;
  } else {
    if (u == 0) *ticket = 0;
  }
}

// ---------- main kernel: r11 + ds_read2-paired corr window + MLP VMEM prefetch ----------
__global__ __launch_bounds__(128, 4)
void mainK(const float* __restrict__ x, const float* __restrict__ y,
           const float* __restrict__ M4, const float* __restrict__ biasT,
           unsigned long long* __restrict__ partials, int* __restrict__ ticket,
           float* __restrict__ out){
  __shared__ float yd[384];     // yd[128+k] = yd[256+k] = y_res[k]
  __shared__ float sVal[2];
  __shared__ int   sIdx[2];
  __shared__ float sL[2], sC[2];
  __shared__ int   sOld;

  const int u = threadIdx.x;               // 0..127 ; u = 64w + l = owned element / output
  const int l = u & 63;
  const int w = u >> 6;
  const long base = (long)blockIdx.x * 128;

  float xlo = x[base + l], xhi = x[base + 64 + l];
  float ylo = y[base + l], yhi = y[base + 64 + l];
  const float yOwn0 = w ? yhi : ylo;
  const bool mOwn = (yOwn0 == IGNORE_OUT);
  float cnt = mOwn ? 0.f : 1.f;
  float lossAcc = 0.f;

  yd[128 + u] = yOwn0; yd[256 + u] = yOwn0;
  __syncthreads();

  for (int i = 0; i < NITER; ++i){
    // ---- prefetch first half of MLP matrix rows (depends only on i,u) ----
    const float4* Mp = (const float4*)(M4 + (size_t)i * 16384);
    float4 pm[16];
    #pragma unroll
    for (int dd = 0; dd < 16; ++dd) pm[dd] = Mp[dd * 128 + u];

    // ---- window-norm prefix at t = 64w+l (DPP scan + DPP sums; zero DS) ----
    float own2 = w ? xhi * xhi : xlo * xlo;
    float oth2 = w ? xlo * xlo : xhi * xhi;
    float v = waveScanInc(own2);
    float osum  = waveSum(oth2);
    float total = readlanef(v, 63) + osum;
    float pref_t = w ? (v + osum) : v;     // inclusive prefix of x^2 at index t

    // ---- ||y_res||^2 ----
    float ny2 = waveSum(ylo * ylo + yhi * yhi);

    // ---- corr: 128 window values via PAIRED LDS reads (ds_read2), snap at j==t ----
    const float* wp = yd + (255 - u);      // base in [128, 255]
    float nt, n1 = 0.f;
    if (w == 0){                           // t = l: snap (serial) in first half
      float c = 0.f;
      #pragma unroll
      for (int j = 0; j < 64; j += 2){
        float w0 = wp[j], w1 = wp[j + 1];  // adjacent dword offsets -> ds_read2_b32
        c = fmaf(w0, readlanef(xlo, j), c);
        n1 = (j == l) ? c : n1;
        c = fmaf(w1, readlanef(xlo, j + 1), c);
        n1 = (j + 1 == l) ? c : n1;
      }
      float s0 = 0.f, s1 = 0.f, s2 = 0.f, s3 = 0.f;
      #pragma unroll
      for (int j = 0; j < 64; j += 4){
        float w0 = wp[64 + j], w1 = wp[64 + j + 1];
        float w2v = wp[64 + j + 2], w3 = wp[64 + j + 3];
        s0 = fmaf(w0,  readlanef(xhi, j + 0), s0);
        s1 = fmaf(w1,  readlanef(xhi, j + 1), s1);
        s2 = fmaf(w2v, readlanef(xhi, j + 2), s2);
        s3 = fmaf(w3,  readlanef(xhi, j + 3), s3);
      }
      nt = c + ((s0 + s1) + (s2 + s3));
    } else {                               // t = 64+l: first half all j<=t (split), snap in second
      float s0 = 0.f, s1 = 0.f, s2 = 0.f, s3 = 0.f;
      #pragma unroll
      for (int j = 0; j < 64; j += 4){
        float w0 = wp[j], w1 = wp[j + 1];
        float w2v = wp[j + 2], w3 = wp[j + 3];
        s0 = fmaf(w0,  readlanef(xlo, j + 0), s0);
        s1 = fmaf(w1,  readlanef(xlo, j + 1), s1);
        s2 = fmaf(w2v, readlanef(xlo, j + 2), s2);
        s3 = fmaf(w3,  readlanef(xlo, j + 3), s3);
      }
      float c = (s0 + s1) + (s2 + s3);
      n1 = c;
      #pragma unroll
      for (int j = 0; j < 64; j += 2){
        float w0 = wp[64 + j], w1 = wp[64 + j + 1];
        c = fmaf(w0, readlanef(xhi, j), c);
        n1 = (j == l) ? c : n1;
        c = fmaf(w1, readlanef(xhi, j + 1), c);
        n1 = (j + 1 == l) ? c : n1;
      }
      nt = c;
    }

    // ---- cosine sims via v_rsq; DPP argmax; cross-wave combine ----
    {
      bool yz = (ny2 == 0.f);
      float rNY = __builtin_amdgcn_rsqf(ny2);       // 1/||y||
      float nx2b = fmaxf(total - pref_t, 0.f);
      float s1v = (yz || pref_t == 0.f) ? 0.f : n1 * __builtin_amdgcn_rsqf(pref_t) * rNY;
      float s2v = (yz || nx2b  == 0.f) ? 0.f : (nt - n1) * __builtin_amdgcn_rsqf(nx2b) * rNY;
      if (u == 127) s2v = -INFINITY;       // shift 255 doesn't exist
      float bv = s1v; int bi = u;
      if (s2v > bv){ bv = s2v; bi = u + 128; }
      waveArgmax(bv, bi);
      if (l == 0){ sVal[w] = bv; sIdx[w] = bi; }
    }
    __syncthreads();                       // B1
    int sstar;
    {
      float v0 = sVal[0], v1 = sVal[1];
      int   i0 = sIdx[0], i1 = sIdx[1];
      sstar = (v1 > v0 || (v1 == v0 && i1 < i0)) ? i1 : i0;
    }

    // ---- x_aug + detached softmax (hw exp2/rcp; paired gathers) ----
    float xa, xb;
    gatherPair(xlo, xhi, sstar + l - 127, xa, xb);
    float ea = __builtin_amdgcn_exp2f(xa * ylo * LOG2E);
    float eb = __builtin_amdgcn_exp2f(xb * yhi * LOG2E);
    float rse = __builtin_amdgcn_rcpf(waveSum(ea + eb));
    float wlo = xa * (ea * rse), whi = xb * (eb * rse);   // xatt

    // ---- x_res update (reverse shift, paired gather) ----
    {
      float ga, gb;
      gatherPair(wlo, whi, l + 127 - sstar, ga, gb);
      xlo -= ga; xhi -= gb;
    }

    // ---- MLP: thread u -> output o = u; prefetched first half + 16 inline b128 ----
    float ye;
    {
      float a0 = 0.f, a1 = 0.f, a2 = 0.f, a3 = 0.f;
      #pragma unroll
      for (int dd = 0; dd < 16; dd += 4){
        float4 m0 = pm[dd + 0], m1 = pm[dd + 1], m2 = pm[dd + 2], m3 = pm[dd + 3];
        a0 = fmaf(m0.x, readlanef(wlo, 4*dd + 0), a0); a0 = fmaf(m0.y, readlanef(wlo, 4*dd + 1), a0);
        a0 = fmaf(m0.z, readlanef(wlo, 4*dd + 2), a0); a0 = fmaf(m0.w, readlanef(wlo, 4*dd + 3), a0);
        a1 = fmaf(m1.x, readlanef(wlo, 4*dd + 4), a1); a1 = fmaf(m1.y, readlanef(wlo, 4*dd + 5), a1);
        a1 = fmaf(m1.z, readlanef(wlo, 4*dd + 6), a1); a1 = fmaf(m1.w, readlanef(wlo, 4*dd + 7), a1);
        a2 = fmaf(m2.x, readlanef(wlo, 4*dd + 8), a2); a2 = fmaf(m2.y, readlanef(wlo, 4*dd + 9), a2);
        a2 = fmaf(m2.z, readlanef(wlo, 4*dd +10), a2); a2 = fmaf(m2.w, readlanef(wlo, 4*dd +11), a2);
        a3 = fmaf(m3.x, readlanef(wlo, 4*dd +12), a3); a3 = fmaf(m3.y, readlanef(wlo, 4*dd +13), a3);
        a3 = fmaf(m3.z, readlanef(wlo, 4*dd +14), a3); a3 = fmaf(m3.w, readlanef(wlo, 4*dd +15), a3);
      }
      #pragma unroll
      for (int dd = 16; dd < 32; dd += 4){
        float4 m0 = Mp[(dd + 0) * 128 + u];
        float4 m1 = Mp[(dd + 1) * 128 + u];
        float4 m2 = Mp[(dd + 2) * 128 + u];
        float4 m3 = Mp[(dd + 3) * 128 + u];
        int b = 4*dd - 64;
        a0 = fmaf(m0.x, readlanef(whi, b + 0), a0); a0 = fmaf(m0.y, readlanef(whi, b + 1), a0);
        a0 = fmaf(m0.z, readlanef(whi, b + 2), a0); a0 = fmaf(m0.w, readlanef(whi, b + 3), a0);
        a1 = fmaf(m1.x, readlanef(whi, b + 4), a1); a1 = fmaf(m1.y, readlanef(whi, b + 5), a1);
        a1 = fmaf(m1.z, readlanef(whi, b + 6), a1); a1 = fmaf(m1.w, readlanef(whi, b + 7), a1);
        a2 = fmaf(m2.x, readlanef(whi, b + 8), a2); a2 = fmaf(m2.y, readlanef(whi, b + 9), a2);
        a2 = fmaf(m2.z, readlanef(whi, b +10), a2); a2 = fmaf(m2.w, readlanef(whi, b +11), a2);
        a3 = fmaf(m3.x, readlanef(whi, b +12), a3); a3 = fmaf(m3.y, readlanef(whi, b +13), a3);
        a3 = fmaf(m3.z, readlanef(whi, b +14), a3); a3 = fmaf(m3.w, readlanef(whi, b +15), a3);
      }
      ye = ((a0 + a1) + (a2 + a3)) + biasT[i * 128 + u];
    }

    // ---- loss on owned element + publish new y_res ----
    {
      float yOwn = w ? yhi : ylo;
      float df = ye - yOwn;
      if (!mOwn) lossAcc = fmaf(df, df, lossAcc);
      float yNew = yOwn - ye;
      yd[128 + u] = yNew; yd[256 + u] = yNew;
    }
    __syncthreads();                       // B2
    ylo = yd[128 + l];                     // refresh register copies from yd
    yhi = yd[192 + l];
  }

  // ---- block loss/cnt, partial store + ticket; last block finalizes ----
  lossAcc = waveSum(lossAcc);
  cnt     = waveSum(cnt);
  if (l == 0){ sL[w] = lossAcc; sC[w] = cnt; }
  __syncthreads();
  if (u == 0){
    union { float2 f; unsigned long long v; } pk;
    pk.f.x = sL[0] + sL[1];
    pk.f.y = sC[0] + sC[1];
    __hip_atomic_store(&partials[blockIdx.x], pk.v, __ATOMIC_RELEASE, __HIP_MEMORY_SCOPE_AGENT);
    sOld = __hip_atomic_fetch_add(ticket, 1, __ATOMIC_ACQ_REL, __HIP_MEMORY_SCOPE_AGENT);
  }
  __syncthreads();
  if (sOld == NBLK - 1){
    float ls = 0.f, cs = 0.f;
    for (int g = u; g < NBLK; g += 128){
      union { float2 f; unsigned long long v; } pk;
      pk.v = __hip_atomic_load(&partials[g], __ATOMIC_ACQUIRE, __HIP_MEMORY_SCOPE_AGENT);
      ls += pk.f.x; cs += pk.f.y;
    }
    ls = waveSum(ls); cs = waveSum(cs);
    if (l == 0){ sL[w] = ls; sC[w] = cs; }
    __syncthreads();
    if (u == 0) out[0] = (sL[0] + sL[1]) / ((float)NITER * (sC[0] + sC[1]));
  }
}

extern "C" void kernel_launch(void* const* d_in, const int* in_sizes, int n_in,
                              void* d_out, int out_size, void* d_ws, size_t ws_size,
                              hipStream_t stream){
  const float* x  = (const float*)d_in[0];
  const float* y  = (const float*)d_in[1];
  const float* w1 = (const float*)d_in[2];
  const float* b1 = (const float*)d_in[3];
  const float* w2 = (const float*)d_in[4];
  const float* b2 = (const float*)d_in[5];
  float* out = (float*)d_out;

  // ws: [0,4) ticket ; [256, 256+256K) M4 ; +2K biasT ; +16K partials
  int*   ticket = (int*)d_ws;
  float* M4     = (float*)((char*)d_ws + 256);
  float* biasT  = (float*)((char*)d_ws + 256 + 4 * 128 * 128 * sizeof(float));
  unsigned long long* partials =
      (unsigned long long*)((char*)d_ws + 256 + 4 * 128 * 128 * sizeof(float) + 4 * 128 * sizeof(float));

  prepK<<<517, 128, 0, stream>>>(w1, b1, w2, b2, M4, biasT, ticket);
  mainK<<<NBLK, 128, 0, stream>>>(x, y, M4, biasT, partials, ticket, out);
}

// Round 13
// 152.054 us; speedup vs baseline: 1.1165x; 1.1165x over previous
//
#include <hip/hip_runtime.h>
#include <math.h>

// B=4, T=512, IDIM=128, HDIM=1024, CDIM=256
#define NROWS 2048
#define NBLK  2048            // one row per block, 2 waves per block
#define NITER 4
#define IGNORE_OUT 10000.0f
#define LOG2E 1.44269504088896340736f

__device__ __forceinline__ float readlanef(float v, int lane){
  return __int_as_float(__builtin_amdgcn_readlane(__float_as_int(v), lane));
}

// ---- DPP wave primitives (gfx9 ladder: row_shr 1/2/4/8, bcast15->rows1,3, bcast31->rows2,3) ----
// inclusive prefix sum across 64 lanes (VALU only, no DS)
__device__ __forceinline__ float waveScanInc(float v){
  v += __int_as_float(__builtin_amdgcn_update_dpp(0, __float_as_int(v), 0x111, 0xF, 0xF, true));
  v += __int_as_float(__builtin_amdgcn_update_dpp(0, __float_as_int(v), 0x112, 0xF, 0xF, true));
  v += __int_as_float(__builtin_amdgcn_update_dpp(0, __float_as_int(v), 0x114, 0xF, 0xF, true));
  v += __int_as_float(__builtin_amdgcn_update_dpp(0, __float_as_int(v), 0x118, 0xF, 0xF, true));
  v += __int_as_float(__builtin_amdgcn_update_dpp(0, __float_as_int(v), 0x142, 0xA, 0xF, true));
  v += __int_as_float(__builtin_amdgcn_update_dpp(0, __float_as_int(v), 0x143, 0xC, 0xF, true));
  return v;                                // lane l = sum of lanes 0..l
}
// full-wave sum, broadcast to all lanes via readlane(63)
__device__ __forceinline__ float waveSum(float v){
  return readlanef(waveScanInc(v), 63);
}
// first-max argmax over (v, i) pairs; result broadcast to all lanes
__device__ __forceinline__ void waveArgmax(float &v, int &i){
#define AMSTEP(ctrl, rm) { \
    float ov = __int_as_float(__builtin_amdgcn_update_dpp(__float_as_int(v), __float_as_int(v), ctrl, rm, 0xF, false)); \
    int   oi = __builtin_amdgcn_update_dpp(i, i, ctrl, rm, 0xF, false); \
    bool take = (ov > v) || (ov == v && oi < i); \
    v = take ? ov : v; i = take ? oi : i; }
  AMSTEP(0x111, 0xF) AMSTEP(0x112, 0xF) AMSTEP(0x114, 0xF)
  AMSTEP(0x118, 0xF) AMSTEP(0x142, 0xA) AMSTEP(0x143, 0xC)
#undef AMSTEP
  v = readlanef(v, 63);
  i = __builtin_amdgcn_readlane(i, 63);
}
// paired gather: a = vec[idx], b = vec[idx+64] (0 outside [0,128)); 2 bpermutes total
__device__ __forceinline__ void gatherPair(float v0, float v1, int idx, float &a, float &b){
  int c = idx & 63;
  float g0 = __shfl(v0, c, 64);
  float g1 = __shfl(v1, c, 64);
  a = ((unsigned)idx < 128u) ? ((idx & 64) ? g1 : g0) : 0.f;
  int idx2 = idx + 64;
  b = ((unsigned)idx2 < 128u) ? ((idx2 & 64) ? g1 : g0) : 0.f;
}

// ---------- prep kernel ----------
__global__ __launch_bounds__(128)
void prepK(const float* __restrict__ w1, const float* __restrict__ b1,
           const float* __restrict__ w2, const float* __restrict__ b2,
           float* __restrict__ M4, float* __restrict__ biasT, int* __restrict__ ticket){
  const int blk = blockIdx.x;
  const int u = threadIdx.x;
  if (blk < 512){
    int i = blk >> 7, o = blk & 127;
    const float* w1p = w1 + (i * 256) * 128 + u;   // coalesced over d=u
    const float* w2p = w2 + o * 1024 + i * 256;    // thread-uniform
    float a = 0.f;
    #pragma unroll 16
    for (int c = 0; c < 256; ++c) a = fmaf(w1p[c * 128], w2p[c], a);
    M4[i * 16384 + (u >> 2) * 512 + o * 4 + (u & 3)] = a;
  } else if (blk < 516){
    int i = blk - 512;
    const float* w2p = w2 + u * 1024 + i * 256;
    const float* b1p = b1 + i * 256;
    float a = b2[u];
    #pragma unroll 8
    for (int c = 0; c < 256; ++c) a = fmaf(b1p[c], w2p[c], a);
    biasT[i * 128 + u] = a;
  } else {
    if (u == 0) *ticket = 0;
  }
}

// ---------- main kernel: r11 optimum — 2 waves/row, LDS b32 window, DPP reductions ----------
// wave w handles shift-pair t = 64w + l (shifts t and t+128), full j range [0,128)
// window value for (t, j) = y[(255 - t + j) % 128] = yd[(255 - t) + j], yd[384] duplicated
__global__ __launch_bounds__(128, 4)
void mainK(const float* __restrict__ x, const float* __restrict__ y,
           const float* __restrict__ M4, const float* __restrict__ biasT,
           unsigned long long* __restrict__ partials, int* __restrict__ ticket,
           float* __restrict__ out){
  __shared__ float yd[384];     // yd[128+k] = yd[256+k] = y_res[k]
  __shared__ float sVal[2];
  __shared__ int   sIdx[2];
  __shared__ float sL[2], sC[2];
  __shared__ int   sOld;

  const int u = threadIdx.x;               // 0..127 ; u = 64w + l = owned element / output
  const int l = u & 63;
  const int w = u >> 6;
  const long base = (long)blockIdx.x * 128;

  float xlo = x[base + l], xhi = x[base + 64 + l];
  float ylo = y[base + l], yhi = y[base + 64 + l];
  const float yOwn0 = w ? yhi : ylo;
  const bool mOwn = (yOwn0 == IGNORE_OUT);
  float cnt = mOwn ? 0.f : 1.f;
  float lossAcc = 0.f;

  yd[128 + u] = yOwn0; yd[256 + u] = yOwn0;
  __syncthreads();

  for (int i = 0; i < NITER; ++i){
    // ---- window-norm prefix at t = 64w+l (DPP scan + DPP sums; zero DS) ----
    float own2 = w ? xhi * xhi : xlo * xlo;
    float oth2 = w ? xlo * xlo : xhi * xhi;
    float v = waveScanInc(own2);
    float osum  = waveSum(oth2);
    float total = readlanef(v, 63) + osum;
    float pref_t = w ? (v + osum) : v;     // inclusive prefix of x^2 at index t

    // ---- ||y_res||^2 ----
    float ny2 = waveSum(ylo * ylo + yhi * yhi);

    // ---- corr: 128 b32 LDS window steps (2 lanes/bank = free), snap at j==t ----
    // split accumulators in the non-snap half to shorten the fma chain
    const float* wp = yd + (255 - u);      // base in [128, 255]
    float nt, n1 = 0.f;
    if (w == 0){                           // t = l: snap (serial) in first half
      float c = 0.f;
      #pragma unroll 8
      for (int j = 0; j < 64; ++j){
        c = fmaf(wp[j], readlanef(xlo, j), c);
        n1 = (j == l) ? c : n1;
      }
      float s0 = 0.f, s1 = 0.f, s2 = 0.f, s3 = 0.f;
      #pragma unroll 8
      for (int j = 0; j < 64; j += 4){
        s0 = fmaf(wp[64 + j + 0], readlanef(xhi, j + 0), s0);
        s1 = fmaf(wp[64 + j + 1], readlanef(xhi, j + 1), s1);
        s2 = fmaf(wp[64 + j + 2], readlanef(xhi, j + 2), s2);
        s3 = fmaf(wp[64 + j + 3], readlanef(xhi, j + 3), s3);
      }
      nt = c + ((s0 + s1) + (s2 + s3));
    } else {                               // t = 64+l: first half all j<=t (split), snap in second
      float s0 = 0.f, s1 = 0.f, s2 = 0.f, s3 = 0.f;
      #pragma unroll 8
      for (int j = 0; j < 64; j += 4){
        s0 = fmaf(wp[j + 0], readlanef(xlo, j + 0), s0);
        s1 = fmaf(wp[j + 1], readlanef(xlo, j + 1), s1);
        s2 = fmaf(wp[j + 2], readlanef(xlo, j + 2), s2);
        s3 = fmaf(wp[j + 3], readlanef(xlo, j + 3), s3);
      }
      float c = (s0 + s1) + (s2 + s3);
      n1 = c;
      #pragma unroll 8
      for (int j = 0; j < 64; ++j){
        c = fmaf(wp[64 + j], readlanef(xhi, j), c);
        n1 = (j == l) ? c : n1;
      }
      nt = c;
    }

    // ---- cosine sims via v_rsq; DPP argmax; cross-wave combine ----
    {
      bool yz = (ny2 == 0.f);
      float rNY = __builtin_amdgcn_rsqf(ny2);       // 1/||y||
      float nx2b = fmaxf(total - pref_t, 0.f);
      float s1v = (yz || pref_t == 0.f) ? 0.f : n1 * __builtin_amdgcn_rsqf(pref_t) * rNY;
      float s2v = (yz || nx2b  == 0.f) ? 0.f : (nt - n1) * __builtin_amdgcn_rsqf(nx2b) * rNY;
      if (u == 127) s2v = -INFINITY;       // shift 255 doesn't exist
      float bv = s1v; int bi = u;
      if (s2v > bv){ bv = s2v; bi = u + 128; }
      waveArgmax(bv, bi);
      if (l == 0){ sVal[w] = bv; sIdx[w] = bi; }
    }
    __syncthreads();                       // B1
    int sstar;
    {
      float v0 = sVal[0], v1 = sVal[1];
      int   i0 = sIdx[0], i1 = sIdx[1];
      sstar = (v1 > v0 || (v1 == v0 && i1 < i0)) ? i1 : i0;
    }

    // ---- x_aug + detached softmax (hw exp2/rcp; paired gathers) ----
    float xa, xb;
    gatherPair(xlo, xhi, sstar + l - 127, xa, xb);
    float ea = __builtin_amdgcn_exp2f(xa * ylo * LOG2E);
    float eb = __builtin_amdgcn_exp2f(xb * yhi * LOG2E);
    float rse = __builtin_amdgcn_rcpf(waveSum(ea + eb));
    float wlo = xa * (ea * rse), whi = xb * (eb * rse);   // xatt

    // ---- x_res update (reverse shift, paired gather) ----
    {
      float ga, gb;
      gatherPair(wlo, whi, l + 127 - sstar, ga, gb);
      xlo -= ga; xhi -= gb;
    }

    // ---- MLP: thread u -> output o = u; 32 b128 loads, 4-way split accumulators ----
    float ye;
    {
      const float4* Mp = (const float4*)(M4 + (size_t)i * 16384);
      float a0 = 0.f, a1 = 0.f, a2 = 0.f, a3 = 0.f;
      #pragma unroll 4
      for (int dd = 0; dd < 16; dd += 4){
        float4 m0 = Mp[(dd + 0) * 128 + u];
        float4 m1 = Mp[(dd + 1) * 128 + u];
        float4 m2 = Mp[(dd + 2) * 128 + u];
        float4 m3 = Mp[(dd + 3) * 128 + u];
        a0 = fmaf(m0.x, readlanef(wlo, 4*dd + 0), a0); a0 = fmaf(m0.y, readlanef(wlo, 4*dd + 1), a0);
        a0 = fmaf(m0.z, readlanef(wlo, 4*dd + 2), a0); a0 = fmaf(m0.w, readlanef(wlo, 4*dd + 3), a0);
        a1 = fmaf(m1.x, readlanef(wlo, 4*dd + 4), a1); a1 = fmaf(m1.y, readlanef(wlo, 4*dd + 5), a1);
        a1 = fmaf(m1.z, readlanef(wlo, 4*dd + 6), a1); a1 = fmaf(m1.w, readlanef(wlo, 4*dd + 7), a1);
        a2 = fmaf(m2.x, readlanef(wlo, 4*dd + 8), a2); a2 = fmaf(m2.y, readlanef(wlo, 4*dd + 9), a2);
        a2 = fmaf(m2.z, readlanef(wlo, 4*dd +10), a2); a2 = fmaf(m2.w, readlanef(wlo, 4*dd +11), a2);
        a3 = fmaf(m3.x, readlanef(wlo, 4*dd +12), a3); a3 = fmaf(m3.y, readlanef(wlo, 4*dd +13), a3);
        a3 = fmaf(m3.z, readlanef(wlo, 4*dd +14), a3); a3 = fmaf(m3.w, readlanef(wlo, 4*dd +15), a3);
      }
      #pragma unroll 4
      for (int dd = 16; dd < 32; dd += 4){
        float4 m0 = Mp[(dd + 0) * 128 + u];
        float4 m1 = Mp[(dd + 1) * 128 + u];
        float4 m2 = Mp[(dd + 2) * 128 + u];
        float4 m3 = Mp[(dd + 3) * 128 + u];
        int b = 4*dd - 64;
        a0 = fmaf(m0.x, readlanef(whi, b + 0), a0); a0 = fmaf(m0.y, readlanef(whi, b + 1), a0);
        a0 = fmaf(m0.z, readlanef(whi, b + 2), a0); a0 = fmaf(m0.w, readlanef(whi, b + 3), a0);
        a1 = fmaf(m1.x, readlanef(whi, b + 4), a1); a1 = fmaf(m1.y, readlanef(whi, b + 5), a1);
        a1 = fmaf(m1.z, readlanef(whi, b + 6), a1); a1 = fmaf(m1.w, readlanef(whi, b + 7), a1);
        a2 = fmaf(m2.x, readlanef(whi, b + 8), a2); a2 = fmaf(m2.y, readlanef(whi, b + 9), a2);
        a2 = fmaf(m2.z, readlanef(whi, b +10), a2); a2 = fmaf(m2.w, readlanef(whi, b +11), a2);
        a3 = fmaf(m3.x, readlanef(whi, b +12), a3); a3 = fmaf(m3.y, readlanef(whi, b +13), a3);
        a3 = fmaf(m3.z, readlanef(whi, b +14), a3); a3 = fmaf(m3.w, readlanef(whi, b +15), a3);
      }
      ye = ((a0 + a1) + (a2 + a3)) + biasT[i * 128 + u];
    }

    // ---- loss on owned element + publish new y_res ----
    {
      float yOwn = w ? yhi : ylo;
      float df = ye - yOwn;
      if (!mOwn) lossAcc = fmaf(df, df, lossAcc);
      float yNew = yOwn - ye;
      yd[128 + u] = yNew; yd[256 + u] = yNew;
    }
    __syncthreads();                       // B2
    ylo = yd[128 + l];                     // refresh register copies from yd
    yhi = yd[192 + l];
  }

  // ---- block loss/cnt, partial store + ticket; last block finalizes ----
  lossAcc = waveSum(lossAcc);
  cnt     = waveSum(cnt);
  if (l == 0){ sL[w] = lossAcc; sC[w] = cnt; }
  __syncthreads();
  if (u == 0){
    union { float2 f; unsigned long long v; } pk;
    pk.f.x = sL[0] + sL[1];
    pk.f.y = sC[0] + sC[1];
    __hip_atomic_store(&partials[blockIdx.x], pk.v, __ATOMIC_RELEASE, __HIP_MEMORY_SCOPE_AGENT);
    sOld = __hip_atomic_fetch_add(ticket, 1, __ATOMIC_ACQ_REL, __HIP_MEMORY_SCOPE_AGENT);
  }
  __syncthreads();
  if (sOld == NBLK - 1){
    float ls = 0.f, cs = 0.f;
    for (int g = u; g < NBLK; g += 128){
      union { float2 f; unsigned long long v; } pk;
      pk.v = __hip_atomic_load(&partials[g], __ATOMIC_ACQUIRE, __HIP_MEMORY_SCOPE_AGENT);
      ls += pk.f.x; cs += pk.f.y;
    }
    ls = waveSum(ls); cs = waveSum(cs);
    if (l == 0){ sL[w] = ls; sC[w] = cs; }
    __syncthreads();
    if (u == 0) out[0] = (sL[0] + sL[1]) / ((float)NITER * (sC[0] + sC[1]));
  }
}

extern "C" void kernel_launch(void* const* d_in, const int* in_sizes, int n_in,
                              void* d_out, int out_size, void* d_ws, size_t ws_size,
                              hipStream_t stream){
  const float* x  = (const float*)d_in[0];
  const float* y  = (const float*)d_in[1];
  const float* w1 = (const float*)d_in[2];
  const float* b1 = (const float*)d_in[3];
  const float* w2 = (const float*)d_in[4];
  const float* b2 = (const float*)d_in[5];
  float* out = (float*)d_out;

  // ws: [0,4) ticket ; [256, 256+256K) M4 ; +2K biasT ; +16K partials
  int*   ticket = (int*)d_ws;
  float* M4     = (float*)((char*)d_ws + 256);
  float* biasT  = (float*)((char*)d_ws + 256 + 4 * 128 * 128 * sizeof(float));
  unsigned long long* partials =
      (unsigned long long*)((char*)d_ws + 256 + 4 * 128 * 128 * sizeof(float) + 4 * 128 * sizeof(float));

  prepK<<<517, 128, 0, stream>>>(w1, b1, w2, b2, M4, biasT, ticket);
  mainK<<<NBLK, 128, 0, stream>>>(x, y, M4, biasT, partials, ticket, out);
}